// Round 8
// baseline (298.029 us; speedup 1.0000x reference)
//
#include <hip/hip_runtime.h>
#include <math.h>

// Problem constants
#define N    130
#define NN   (130*130)       // 16900
#define NNN  (130*130*130)   // 2197000
#define NQ4  (NNN/4)         // 549250
#define NCH  12
#define XN   128
#define XNN  (XN*XN)

// Fused-kernel tiling (R7 structure: 1 voxel-column per thread, DPP w-box)
#define WT   11              // w tiles: 16 lanes -> 12 valid w (2+2 halo)
#define HT   11              // h tiles: 16 rows  -> 12 valid h (2+2 halo)
#define DSEGS 13             // d strips of exactly 10 output planes
#define NWG  (WT*HT*DSEGS)   // 1573 blocks

typedef float f32x4 __attribute__((ext_vector_type(4)));

// DPP lane-shift within 16-lane rows (VALU pipe, no LDS).
template <int CTRL>
__device__ __forceinline__ float dppf(float v) {
    return __int_as_float(__builtin_amdgcn_update_dpp(
        0, __float_as_int(v), CTRL, 0xF, 0xF, true));
}
#define W5(v) ((v) + dppf<0x111>(v) + dppf<0x112>(v) \
                   + dppf<0x101>(v) + dppf<0x102>(v))

// ---------------------------------------------------------------------------
// R8 = ABLATION ROUND. Same R7 kernel as template<MODE>:
//   MODE 1: front-end only   (6 loads + diff^2 + DPP w-box)
//   MODE 2: + LDS exchange + raw barrier + h-box + d-ring + min/mean
//   MODE 3: + mvar/inv + 12x __expf           (no global stores)
//   MODE 4: full (real output + MV + reductions)  <- the only writer of out
// MODE<4 keep all computed values live via `probe` stored to MV (workspace),
// which the MODE-4 pass fully overwrites before k_fix reads it.
// Per-dispatch durations from rocprof give the stage decomposition.
// ---------------------------------------------------------------------------
template <int MODE>
__global__ __launch_bounds__(256) void k_fused(const float* __restrict__ x,
                                               float* __restrict__ Cout,
                                               float* __restrict__ MV,
                                               double* __restrict__ acc,
                                               unsigned* __restrict__ gmm) {
    const int tid = threadIdx.x;
    const int wl  = tid & 15;
    const int r   = tid >> 4;

    // bijective XCD-chunk swizzle (nwg = 1573 = 8*196 + 5)
    const int qq  = NWG >> 3, rm = NWG & 7;
    const int xcd = blockIdx.x & 7, idx = blockIdx.x >> 3;
    const int b   = (xcd < rm ? xcd * (qq + 1)
                              : rm * (qq + 1) + (xcd - rm) * qq) + idx;

    const int wt   = b % WT;
    const int rest = b / WT;
    const int ht   = rest % HT;
    const int ds   = rest / HT;

    const int W0 = wt * 12;
    const int H0 = ht * 12;
    const int D0 = ds * 10;

    const int  w_gl = W0 + wl - 2;                      // global w (halo +-2)
    const int  bw   = min(max(w_gl, 0), 129);           // edge-clamped column
    const int  ghW  = min(max(H0 - 2 + r, 0), 129);     // W row (replicated)
    const int  oh   = H0 + r - 2;                       // output row
    const bool interior = (r >= 2) && (r < 14);
    const bool validw   = (wl >= 2) && (wl < 14) && (w_gl < N);
    const bool valid    = interior && (oh < N) && validw;

    // h-dim precompute (thread-invariant)
    const int   ih_c = min(max(ghW - 1, 0), 127);
    const float fhm  = (ghW >= 1)   ? 1.0f : 0.0f;
    const float fhp  = (ghW <= 128) ? 1.0f : 0.0f;
    const int   dhm  = (min(max(ghW - 3, 0), 127) - ih_c) * XN;
    const int   dhp  = (min(ghW + 1, 127)        - ih_c) * XN;

    // w-dim per-thread column offsets
    const int   col_c = ih_c * XN + min(max(bw - 1, 0), 127);
    const int   col_m = ih_c * XN + min(max(bw - 3, 0), 127);
    const int   col_p = ih_c * XN + min(bw + 1, 127);
    const float fw_m  = (bw >= 1)   ? 1.0f : 0.0f;
    const float fw_p  = (bw <= 128) ? 1.0f : 0.0f;

    __shared__ f32x4 Wlds[2][3][16][16];   // double-buffered plane, 24 KB
    __shared__ float red[256];

    f32x4 ring[5][3];
    float lsum  = 0.0f;
    float mn_mv = INFINITY, mx_mv = 0.0f;
    float probe = 0.0f;                    // DCE guard for MODE<4
    int   voxoff = D0 * NN + oh * N + (valid ? w_gl : 0);

    float PF, fdpP;

#define PRE(IT) do {                                                          \
    const int dcn = min(max(D0 - 2 + (IT), 0), 129);                          \
    PF   = x[(size_t)(min(dcn + 1, 127)) * XNN + col_c];                      \
    fdpP = (dcn <= 128) ? 1.0f : 0.0f;                                        \
} while (0)

#define STEP(IT, SLOT, DOUT) do {                                             \
    const int it_ = (IT);                                                     \
    const int dc  = min(max(D0 - 2 + it_, 0), 129);                           \
    const float* pc = x + (size_t)(min(max(dc - 1, 0), 127)) * XNN;           \
    const float* pm = x + (size_t)(min(max(dc - 3, 0), 127)) * XNN;           \
    const float fdm = (dc >= 1) ? 1.0f : 0.0f;                                \
    const float y1 = PF * fdpP;                                               \
    PRE(it_ + 1);                                                             \
    const float y0 = pm[col_c]       * fdm;                                   \
    const float y2 = pc[col_c + dhm] * fhm;                                   \
    const float y3 = pc[col_c + dhp] * fhp;                                   \
    const float y4 = pc[col_m]       * fw_m;                                  \
    const float y5 = pc[col_p]       * fw_p;                                  \
    float Wa[12];                                                             \
    { float t;                                                                \
      t = y4 - y0; Wa[0]  = t * t;  t = y2 - y0; Wa[1]  = t * t;              \
      t = y2 - y4; Wa[2]  = t * t;  t = y5 - y0; Wa[3]  = t * t;              \
      t = y5 - y2; Wa[4]  = t * t;  t = y1 - y4; Wa[5]  = t * t;              \
      t = y1 - y2; Wa[6]  = t * t;  t = y1 - y5; Wa[7]  = t * t;              \
      t = y3 - y0; Wa[8]  = t * t;  t = y3 - y4; Wa[9]  = t * t;              \
      t = y3 - y5; Wa[10] = t * t;  t = y3 - y1; Wa[11] = t * t; }            \
    _Pragma("unroll") for (int z = 0; z < 12; ++z) Wa[z] = W5(Wa[z]);         \
    if constexpr (MODE == 1) {                                                \
        _Pragma("unroll") for (int z = 0; z < 12; ++z) probe += Wa[z];        \
    } else {                                                                  \
    const int pb = it_ & 1;                                                   \
    Wlds[pb][0][r][wl] = (f32x4){Wa[0], Wa[1], Wa[2],  Wa[3]};                \
    Wlds[pb][1][r][wl] = (f32x4){Wa[4], Wa[5], Wa[6],  Wa[7]};                \
    Wlds[pb][2][r][wl] = (f32x4){Wa[8], Wa[9], Wa[10], Wa[11]};               \
    asm volatile("s_waitcnt lgkmcnt(0)" ::: "memory");                        \
    __builtin_amdgcn_s_barrier();                                             \
    if (interior) {                                                           \
        _Pragma("unroll") for (int g = 0; g < 3; ++g) {                       \
            f32x4 a = Wlds[pb][g][r - 2][wl];                                 \
            a += Wlds[pb][g][r - 1][wl];                                      \
            a += Wlds[pb][g][r    ][wl];                                      \
            a += Wlds[pb][g][r + 1][wl];                                      \
            a += Wlds[pb][g][r + 2][wl];                                      \
            ring[SLOT][g] = a;                                                \
        }                                                                     \
        if (DOUT) {                                                           \
            f32x4 sg[3];                                                      \
            _Pragma("unroll") for (int g = 0; g < 3; ++g) {                   \
                f32x4 a = ring[0][g];                                         \
                a += ring[1][g]; a += ring[2][g];                             \
                a += ring[3][g]; a += ring[4][g];                             \
                sg[g] = a * (1.0f / 125.0f);                                  \
            }                                                                 \
            float sv[12];                                                     \
            _Pragma("unroll") for (int g = 0; g < 3; ++g) {                   \
                sv[4*g+0] = sg[g].x; sv[4*g+1] = sg[g].y;                     \
                sv[4*g+2] = sg[g].z; sv[4*g+3] = sg[g].w;                     \
            }                                                                 \
            float mn = sv[0], tt = sv[0];                                     \
            _Pragma("unroll") for (int z = 1; z < 12; ++z) {                  \
                mn = fminf(mn, sv[z]); tt += sv[z];                           \
            }                                                                 \
            if (valid) {                                                      \
                if constexpr (MODE == 2) {                                    \
                    probe += tt - mn;                                         \
                } else {                                                      \
                    const float mvar = tt * (1.0f / 12.0f) - mn;              \
                    const float inv  = 1.0f / fmaxf(mvar, 1e-20f);            \
                    if constexpr (MODE == 3) {                                \
                        float es = 0.0f;                                      \
                        _Pragma("unroll") for (int z = 0; z < 12; ++z)        \
                            es += __expf(-(sv[z] - mn) * inv);                \
                        probe += es + mvar;                                   \
                    } else {                                                  \
                        _Pragma("unroll") for (int z = 0; z < 12; ++z)        \
                            Cout[(size_t)z * NNN + (unsigned)voxoff] =        \
                                __expf(-(sv[z] - mn) * inv);                  \
                        MV[(unsigned)voxoff] = mvar;                          \
                        lsum += mvar;                                         \
                        mn_mv = fminf(mn_mv, mvar);                           \
                        mx_mv = fmaxf(mx_mv, mvar);                           \
                    }                                                         \
                }                                                             \
                voxoff += NN;                                                 \
            }                                                                 \
        }                                                                     \
    }                                                                         \
    }                                                                         \
} while (0)

    PRE(0);
    STEP(0, 0, false);
    STEP(1, 1, false);
    STEP(2, 2, false);
    STEP(3, 3, false);
    STEP(4, 4, true);  STEP(5, 0, true);  STEP(6, 1, true);
    STEP(7, 2, true);  STEP(8, 3, true);
    STEP(9, 4, true);  STEP(10, 0, true); STEP(11, 1, true);
    STEP(12, 2, true); STEP(13, 3, true);
#undef STEP
#undef PRE

    if constexpr (MODE == 4) {
        // block reductions: sum, min, max of mvar
        red[tid] = lsum;
        __syncthreads();
        for (int st = 128; st > 0; st >>= 1) {
            if (tid < st) red[tid] += red[tid + st];
            __syncthreads();
        }
        if (tid == 0) atomicAdd(acc, (double)red[0]);
        __syncthreads();
        red[tid] = mn_mv;
        __syncthreads();
        for (int st = 128; st > 0; st >>= 1) {
            if (tid < st) red[tid] = fminf(red[tid], red[tid + st]);
            __syncthreads();
        }
        if (tid == 0) atomicMin(&gmm[0], __float_as_uint(red[0]));
        __syncthreads();
        red[tid] = mx_mv;
        __syncthreads();
        for (int st = 128; st > 0; st >>= 1) {
            if (tid < st) red[tid] = fmaxf(red[tid], red[tid + st]);
            __syncthreads();
        }
        if (tid == 0) atomicMax(&gmm[1], __float_as_uint(red[0]));
    } else {
        // keep everything live; MV is fully overwritten by the MODE-4 pass
        MV[(unsigned)(blockIdx.x * 256 + tid)] = probe;
    }
}

// zero/init the reduction cells
__global__ void k_zero(double* acc, unsigned* gmm) {
    if (blockIdx.x == 0 && threadIdx.x == 0) {
        *acc = 0.0;
        gmm[0] = 0xFFFFFFFFu;
        gmm[1] = 0u;
    }
}

// k_fix: apply the global-mean clip only where it binds (uniform early-out
// when it never does).
__global__ __launch_bounds__(256) void k_fix(float* __restrict__ io,
                                             const float* __restrict__ MV,
                                             const double* __restrict__ acc,
                                             const unsigned* __restrict__ gmm) {
    const float mv_mean = (float)(*acc * (1.0 / (double)NNN));
    const float lo = mv_mean * 0.001f, hi = mv_mean * 1000.0f;
    const float gmin = __uint_as_float(gmm[0]);
    const float gmax = __uint_as_float(gmm[1]);
    if (gmin >= lo && gmax <= hi) return;
    for (int q = blockIdx.x * 256 + threadIdx.x; q < NQ4;
         q += gridDim.x * 256) {
        const f32x4 mv = *((const f32x4*)MV + q);
        #pragma unroll
        for (int k = 0; k < 4; ++k) {
            const float used = fmaxf(mv[k], 1e-20f);
            const float cl   = fminf(fmaxf(mv[k], lo), hi);
            const float e    = used / cl;
            if (fabsf(e - 1.0f) > 1e-6f) {
                const size_t vox = (size_t)q * 4 + k;
                #pragma unroll
                for (int o = 0; o < NCH; ++o) {
                    const float v = io[(size_t)o * NNN + vox];
                    if (v > 0.0f)
                        io[(size_t)o * NNN + vox] = __powf(v, e);
                }
            }
        }
    }
}

extern "C" void kernel_launch(void* const* d_in, const int* in_sizes, int n_in,
                              void* d_out, int out_size, void* d_ws, size_t ws_size,
                              hipStream_t stream) {
    const float* x = (const float*)d_in[0];
    float* out = (float*)d_out;                 // [12,130,130,130] f32
    float* MV  = (float*)d_ws;                  // mvar plane, NNN floats
    double*  acc = (double*)((char*)d_ws + (size_t)NNN * sizeof(float));
    unsigned* gmm = (unsigned*)((char*)d_ws + (size_t)NNN * sizeof(float) + 8);

    // --- ablation probes (write only to MV scratch; timed via rocprof) ---
    k_fused<1><<<NWG, 256, 0, stream>>>(x, out, MV, acc, gmm);
    k_fused<2><<<NWG, 256, 0, stream>>>(x, out, MV, acc, gmm);
    k_fused<3><<<NWG, 256, 0, stream>>>(x, out, MV, acc, gmm);
    // --- real pass ---
    k_zero <<<1, 64, 0, stream>>>(acc, gmm);
    k_fused<4><<<NWG, 256, 0, stream>>>(x, out, MV, acc, gmm);
    k_fix  <<<1024, 256, 0, stream>>>(out, MV, acc, gmm);
}

// Round 9
// 183.129 us; speedup vs baseline: 1.6274x; 1.6274x over previous
//
#include <hip/hip_runtime.h>
#include <math.h>

// Problem constants
#define N    130
#define NN   (130*130)       // 16900
#define NNN  (130*130*130)   // 2197000
#define NQ4  (NNN/4)         // 549250
#define NCH  12
#define XN   128
#define XNN  (XN*XN)

// Fused-kernel tiling (1 voxel-column per thread, DPP w-box)
#define WT   11              // w tiles: 16 lanes -> 12 valid w (2+2 halo)
#define HT   11              // h tiles: 16 rows  -> 12 valid h (2+2 halo)
#define DSEGS 13             // d strips of exactly 10 output planes
#define NWG  (WT*HT*DSEGS)   // 1573 blocks

typedef float f32x4 __attribute__((ext_vector_type(4)));

// DPP lane-shift within 16-lane rows (VALU pipe, no LDS).
template <int CTRL>
__device__ __forceinline__ float dppf(float v) {
    return __int_as_float(__builtin_amdgcn_update_dpp(
        0, __float_as_int(v), CTRL, 0xF, 0xF, true));
}
#define W5(v) ((v) + dppf<0x111>(v) + dppf<0x112>(v) \
                   + dppf<0x101>(v) + dppf<0x102>(v))

// ---------------------------------------------------------------------------
// R9 change vs R7 (informed by the R8 ablation: front-end ~5us, exp/stores
// ~0, LDS/barrier section ~92us of 97): SINGLE-buffered LDS plane exchange.
// The double buffer (25.6 KB) limited residency to ~2 blocks/CU (occupancy
// counter consistently tracks a ~64 KB effective LDS pool), leaving ~2
// waves/SIMD -- too few to hide the per-step LDS read+add dependency chain.
// Halving LDS to 12.3 KB doubles-to-triples resident blocks; the WAR hazard
// the second buffer used to cover is handled by a second raw barrier per
// step (barrier cost measured ~0 in R2->R4).
// ---------------------------------------------------------------------------
__global__ __launch_bounds__(256) void k_fused(const float* __restrict__ x,
                                               float* __restrict__ Cout,
                                               float* __restrict__ MV,
                                               double* __restrict__ acc,
                                               unsigned* __restrict__ gmm) {
    const int tid = threadIdx.x;
    const int wl  = tid & 15;
    const int r   = tid >> 4;

    // bijective XCD-chunk swizzle (nwg = 1573 = 8*196 + 5)
    const int qq  = NWG >> 3, rm = NWG & 7;
    const int xcd = blockIdx.x & 7, idx = blockIdx.x >> 3;
    const int b   = (xcd < rm ? xcd * (qq + 1)
                              : rm * (qq + 1) + (xcd - rm) * qq) + idx;

    const int wt   = b % WT;
    const int rest = b / WT;
    const int ht   = rest % HT;
    const int ds   = rest / HT;

    const int W0 = wt * 12;
    const int H0 = ht * 12;
    const int D0 = ds * 10;

    const int  w_gl = W0 + wl - 2;                      // global w (halo +-2)
    const int  bw   = min(max(w_gl, 0), 129);           // edge-clamped column
    const int  ghW  = min(max(H0 - 2 + r, 0), 129);     // W row (replicated)
    const int  oh   = H0 + r - 2;                       // output row
    const bool interior = (r >= 2) && (r < 14);
    const bool validw   = (wl >= 2) && (wl < 14) && (w_gl < N);
    const bool valid    = interior && (oh < N) && validw;

    // h-dim precompute (thread-invariant)
    const int   ih_c = min(max(ghW - 1, 0), 127);
    const float fhm  = (ghW >= 1)   ? 1.0f : 0.0f;
    const float fhp  = (ghW <= 128) ? 1.0f : 0.0f;
    const int   dhm  = (min(max(ghW - 3, 0), 127) - ih_c) * XN;
    const int   dhp  = (min(ghW + 1, 127)        - ih_c) * XN;

    // w-dim per-thread column offsets
    const int   col_c = ih_c * XN + min(max(bw - 1, 0), 127);
    const int   col_m = ih_c * XN + min(max(bw - 3, 0), 127);
    const int   col_p = ih_c * XN + min(bw + 1, 127);
    const float fw_m  = (bw >= 1)   ? 1.0f : 0.0f;
    const float fw_p  = (bw <= 128) ? 1.0f : 0.0f;

    __shared__ f32x4 Wlds[3][16][16];   // SINGLE-buffered plane, 12.3 KB

    f32x4 ring[5][3];                   // 5-deep d ring, 12 ch as 3x f32x4
    float lsum  = 0.0f;
    float mn_mv = INFINITY, mx_mv = 0.0f;
    int   voxoff = D0 * NN + oh * N + (valid ? w_gl : 0);

    float PF, fdpP;

#define PRE(IT) do {                                                          \
    const int dcn = min(max(D0 - 2 + (IT), 0), 129);                          \
    PF   = x[(size_t)(min(dcn + 1, 127)) * XNN + col_c];                      \
    fdpP = (dcn <= 128) ? 1.0f : 0.0f;                                        \
} while (0)

#define STEP(IT, SLOT, DOUT) do {                                             \
    const int it_ = (IT);                                                     \
    const int dc  = min(max(D0 - 2 + it_, 0), 129);                           \
    const float* pc = x + (size_t)(min(max(dc - 1, 0), 127)) * XNN;           \
    const float* pm = x + (size_t)(min(max(dc - 3, 0), 127)) * XNN;           \
    const float fdm = (dc >= 1) ? 1.0f : 0.0f;                                \
    const float y1 = PF * fdpP;          /* prefetched cold plane */          \
    PRE(it_ + 1);                        /* issue next cold load early */     \
    const float y0 = pm[col_c]       * fdm;                                   \
    const float y2 = pc[col_c + dhm] * fhm;                                   \
    const float y3 = pc[col_c + dhp] * fhp;                                   \
    const float y4 = pc[col_m]       * fw_m;                                  \
    const float y5 = pc[col_p]       * fw_p;                                  \
    float Wa[12];                                                             \
    { float t;                                                                \
      t = y4 - y0; Wa[0]  = t * t;  t = y2 - y0; Wa[1]  = t * t;              \
      t = y2 - y4; Wa[2]  = t * t;  t = y5 - y0; Wa[3]  = t * t;              \
      t = y5 - y2; Wa[4]  = t * t;  t = y1 - y4; Wa[5]  = t * t;              \
      t = y1 - y2; Wa[6]  = t * t;  t = y1 - y5; Wa[7]  = t * t;              \
      t = y3 - y0; Wa[8]  = t * t;  t = y3 - y4; Wa[9]  = t * t;              \
      t = y3 - y5; Wa[10] = t * t;  t = y3 - y1; Wa[11] = t * t; }            \
    _Pragma("unroll") for (int z = 0; z < 12; ++z) Wa[z] = W5(Wa[z]);         \
    /* barrier A: all waves done READING the previous plane (WAR guard)  */   \
    asm volatile("s_waitcnt lgkmcnt(0)" ::: "memory");                        \
    __builtin_amdgcn_s_barrier();                                             \
    Wlds[0][r][wl] = (f32x4){Wa[0], Wa[1], Wa[2],  Wa[3]};                    \
    Wlds[1][r][wl] = (f32x4){Wa[4], Wa[5], Wa[6],  Wa[7]};                    \
    Wlds[2][r][wl] = (f32x4){Wa[8], Wa[9], Wa[10], Wa[11]};                   \
    /* barrier B: writes visible; global loads/stores stay in flight      */  \
    asm volatile("s_waitcnt lgkmcnt(0)" ::: "memory");                        \
    __builtin_amdgcn_s_barrier();                                             \
    if (interior) {                                                           \
        _Pragma("unroll") for (int g = 0; g < 3; ++g) {                       \
            f32x4 a = Wlds[g][r - 2][wl];                                     \
            a += Wlds[g][r - 1][wl];                                          \
            a += Wlds[g][r    ][wl];                                          \
            a += Wlds[g][r + 1][wl];                                          \
            a += Wlds[g][r + 2][wl];                                          \
            ring[SLOT][g] = a;                                                \
        }                                                                     \
        if (DOUT) {                                                           \
            f32x4 sg[3];                                                      \
            _Pragma("unroll") for (int g = 0; g < 3; ++g) {                   \
                f32x4 a = ring[0][g];                                         \
                a += ring[1][g]; a += ring[2][g];                             \
                a += ring[3][g]; a += ring[4][g];                             \
                sg[g] = a * (1.0f / 125.0f);                                  \
            }                                                                 \
            float sv[12];                                                     \
            _Pragma("unroll") for (int g = 0; g < 3; ++g) {                   \
                sv[4*g+0] = sg[g].x; sv[4*g+1] = sg[g].y;                     \
                sv[4*g+2] = sg[g].z; sv[4*g+3] = sg[g].w;                     \
            }                                                                 \
            float mn = sv[0], tt = sv[0];                                     \
            _Pragma("unroll") for (int z = 1; z < 12; ++z) {                  \
                mn = fminf(mn, sv[z]); tt += sv[z];                           \
            }                                                                 \
            if (valid) {                                                      \
                const float mvar = tt * (1.0f / 12.0f) - mn;                  \
                const float inv  = 1.0f / fmaxf(mvar, 1e-20f);                \
                _Pragma("unroll") for (int z = 0; z < 12; ++z)                \
                    Cout[(size_t)z * NNN + (unsigned)voxoff] =                \
                        __expf(-(sv[z] - mn) * inv);                          \
                MV[(unsigned)voxoff] = mvar;                                  \
                lsum += mvar;                                                 \
                mn_mv = fminf(mn_mv, mvar);                                   \
                mx_mv = fmaxf(mx_mv, mvar);                                   \
                voxoff += NN;                                                 \
            }                                                                 \
        }                                                                     \
    }                                                                         \
} while (0)

    PRE(0);
    // warmup: fill ring slots 0..3 (box planes D0-2 .. D0+1, clamped)
    STEP(0, 0, false);
    STEP(1, 1, false);
    STEP(2, 2, false);
    STEP(3, 3, false);
    // main: 10 output planes; ring slots stay compile-time
    STEP(4, 4, true);  STEP(5, 0, true);  STEP(6, 1, true);
    STEP(7, 2, true);  STEP(8, 3, true);
    STEP(9, 4, true);  STEP(10, 0, true); STEP(11, 1, true);
    STEP(12, 2, true); STEP(13, 3, true);
#undef STEP
#undef PRE

    // block reductions: sum, min, max of mvar (red overlays Wlds)
    __syncthreads();
    float* red = (float*)Wlds;
    red[tid] = lsum;
    __syncthreads();
    for (int st = 128; st > 0; st >>= 1) {
        if (tid < st) red[tid] += red[tid + st];
        __syncthreads();
    }
    if (tid == 0) atomicAdd(acc, (double)red[0]);
    __syncthreads();
    red[tid] = mn_mv;
    __syncthreads();
    for (int st = 128; st > 0; st >>= 1) {
        if (tid < st) red[tid] = fminf(red[tid], red[tid + st]);
        __syncthreads();
    }
    if (tid == 0) atomicMin(&gmm[0], __float_as_uint(red[0]));
    __syncthreads();
    red[tid] = mx_mv;
    __syncthreads();
    for (int st = 128; st > 0; st >>= 1) {
        if (tid < st) red[tid] = fmaxf(red[tid], red[tid + st]);
        __syncthreads();
    }
    if (tid == 0) atomicMax(&gmm[1], __float_as_uint(red[0]));
}

// zero/init the reduction cells
__global__ void k_zero(double* acc, unsigned* gmm) {
    if (blockIdx.x == 0 && threadIdx.x == 0) {
        *acc = 0.0;
        gmm[0] = 0xFFFFFFFFu;
        gmm[1] = 0u;
    }
}

// k_fix: apply the global-mean clip only where it binds (uniform early-out
// when it never does). Pass 1 wrote out = exp(-mind/max(mvar,1e-20));
// clipped-correct value is out^(mvar_used/mvar_clipped).
__global__ __launch_bounds__(256) void k_fix(float* __restrict__ io,
                                             const float* __restrict__ MV,
                                             const double* __restrict__ acc,
                                             const unsigned* __restrict__ gmm) {
    const float mv_mean = (float)(*acc * (1.0 / (double)NNN));
    const float lo = mv_mean * 0.001f, hi = mv_mean * 1000.0f;
    const float gmin = __uint_as_float(gmm[0]);
    const float gmax = __uint_as_float(gmm[1]);
    if (gmin >= lo && gmax <= hi) return;
    for (int q = blockIdx.x * 256 + threadIdx.x; q < NQ4;
         q += gridDim.x * 256) {
        const f32x4 mv = *((const f32x4*)MV + q);
        #pragma unroll
        for (int k = 0; k < 4; ++k) {
            const float used = fmaxf(mv[k], 1e-20f);
            const float cl   = fminf(fmaxf(mv[k], lo), hi);
            const float e    = used / cl;
            if (fabsf(e - 1.0f) > 1e-6f) {
                const size_t vox = (size_t)q * 4 + k;
                #pragma unroll
                for (int o = 0; o < NCH; ++o) {
                    const float v = io[(size_t)o * NNN + vox];
                    if (v > 0.0f)
                        io[(size_t)o * NNN + vox] = __powf(v, e);
                }
            }
        }
    }
}

extern "C" void kernel_launch(void* const* d_in, const int* in_sizes, int n_in,
                              void* d_out, int out_size, void* d_ws, size_t ws_size,
                              hipStream_t stream) {
    const float* x = (const float*)d_in[0];
    float* out = (float*)d_out;                 // [12,130,130,130] f32
    float* MV  = (float*)d_ws;                  // mvar plane, NNN floats
    double*  acc = (double*)((char*)d_ws + (size_t)NNN * sizeof(float));
    unsigned* gmm = (unsigned*)((char*)d_ws + (size_t)NNN * sizeof(float) + 8);

    k_zero <<<1, 64, 0, stream>>>(acc, gmm);
    k_fused<<<NWG, 256, 0, stream>>>(x, out, MV, acc, gmm);  // 1573 blocks
    k_fix  <<<1024, 256, 0, stream>>>(out, MV, acc, gmm);
}